// Round 7
// baseline (1077.507 us; speedup 1.0000x reference)
//
#include <hip/hip_runtime.h>
#include <hip/hip_bf16.h>

#define NN 1024
#define HID 128
#define NHEADS 4
#define HDD 32
#define NL 3
#define NBLK 512     // 2 blocks/CU (4-wave blocks, VGPR<=256 => capacity 2/CU => co-resident)
#define TIB 2        // i-rows per block (= per wave; all 4 waves = 4 heads share both rows)
#define STRJ 1032    // padded j-stride for transposed arrays

// ---- ws layout (float-word units) ----
constexpr int OFF_CONV = 16;
constexpr int OFF_NF   = OFF_CONV;            // 3072
constexpr int OFF_WP   = OFF_NF  + 3072;      // 384
constexpr int OFF_BP   = OFF_WP  + 384;       // 128
constexpr int OFF_WL   = OFF_BP  + 128;       // 49152
constexpr int OFF_WR   = OFF_WL  + 49152;     // 49152
constexpr int OFF_WVW  = OFF_WR  + 49152;     // 49152
constexpr int OFF_ATT  = OFF_WVW + 49152;     // 96
constexpr int OFF_GAM  = OFF_ATT + 96;        // 384
constexpr int OFF_BET  = OFF_GAM + 384;       // 384
constexpr int OFF_WN1  = OFF_BET + 384;       // 8192
constexpr int OFF_BN1  = OFF_WN1 + 8192;      // 64
constexpr int OFF_WN2  = OFF_BN1 + 64;        // 64
constexpr int OFF_BN2  = OFF_WN2 + 64;        // 1
constexpr int OFF_WD1  = OFF_BN2 + 1;         // 8192
constexpr int OFF_BD1  = OFF_WD1 + 8192;      // 64
constexpr int OFF_WD2  = OFF_BD1 + 64;        // 128
constexpr int OFF_BD2  = OFF_WD2 + 128;       // 2
constexpr int OFF_WV1  = OFF_BD2 + 2;         // 8192
constexpr int OFF_BV1  = OFF_WV1 + 8192;      // 64
constexpr int OFF_WV2  = OFF_BV1 + 64;        // 64
constexpr int OFF_BV2  = OFF_WV2 + 64;        // 1
constexpr int OFF_CONV_END = OFF_BV2 + 1;
constexpr int CONV_TOTAL = OFF_CONV_END - OFF_CONV;
constexpr int OFF_MASK = 176960;              // 1024*32 uint32 words
constexpr int OFF_H    = OFF_MASK + NN*32;
constexpr int OFF_WLH  = OFF_H   + NN*HID;    // row-major [i][hd]
constexpr int OFF_WRT  = OFF_WLH + NN*HID;    // TRANSPOSED [hd][j], stride STRJ
constexpr int OFF_WVT  = OFF_WRT + HID*STRJ;  // TRANSPOSED [hd][j], stride STRJ
constexpr int OFF_POOL = OFF_WVT + HID*STRJ;  // 128 floats
constexpr int OFF_CNT  = OFF_POOL + HID;      // barrier counter (u32)
constexpr int OFF_GEN  = OFF_CNT + 1;         // barrier generation (u32)

__device__ __forceinline__ float bf2f(unsigned short u) {
    return __uint_as_float(((unsigned)u) << 16);
}
__device__ __forceinline__ float ldf(const void* p, int idx, bool bf) {
    return bf ? bf2f(((const unsigned short*)p)[idx]) : ((const float*)p)[idx];
}
__device__ __forceinline__ void store_out(void* out, int idx, float v, bool bf) {
    if (bf) {
        unsigned u = __float_as_uint(v);
        unsigned r = (u + 0x7FFFu + ((u >> 16) & 1u)) >> 16;
        ((unsigned short*)out)[idx] = (unsigned short)r;
    } else {
        ((float*)out)[idx] = v;
    }
}
__device__ __forceinline__ bool detect_bf(const unsigned* nf) {
    unsigned w = nf[threadIdx.x & 63];
    int e = (int)((w >> 23) & 0xFFu);
    unsigned long long b = __ballot(e >= 110 && e <= 140);
    return __popcll(b) < 32;
}

struct P21 { const void* p[21]; };
__device__ const int g_sizes[21] = {3072,384,128,49152,49152,49152,96,384,384,
                                    8192,64,64,1,8192,64,128,2,8192,64,64,1};
__device__ const int g_dsts[21] = {OFF_NF,OFF_WP,OFF_BP,OFF_WL,OFF_WR,OFF_WVW,OFF_ATT,
                                   OFF_GAM,OFF_BET,OFF_WN1,OFF_BN1,OFF_WN2,OFF_BN2,
                                   OFF_WD1,OFF_BD1,OFF_WD2,OFF_BD2,OFF_WV1,OFF_BV1,
                                   OFF_WV2,OFF_BV2};

// ---- setup: zero barrier/pool + convert params + adj->bitmask + h0 ----
__global__ __launch_bounds__(256) void k_setup(P21 in, const void* adj, const unsigned* nf,
                                               float* ws) {
    bool bf = detect_bf(nf);
    int b = blockIdx.x, t = threadIdx.x;
    int gid = b * 256 + t;

    if (b == 0 && t < HID + 2) ws[OFF_POOL + t] = 0.0f;  // pooled + cnt + gen

    if (gid < CONV_TOTAL) {
        int rem = gid, s = 0;
        while (s < 21 && rem >= g_sizes[s]) { rem -= g_sizes[s]; s++; }
        if (s < 21) ws[g_dsts[s] + rem] = ldf(in.p[s], rem, bf);
    }

    unsigned* mask = (unsigned*)(ws + OFF_MASK);
    int lane = t & 63, wv = t >> 6;
    for (int p = 0; p < 4; p++) {
        int j = p * 256 + t;
        float v = ldf(adj, b * NN + j, bf);
        unsigned long long bl = __ballot(v > 0.5f);
        if (lane == 0) {
            mask[b * 32 + p * 8 + wv * 2]     = (unsigned)bl;
            mask[b * 32 + p * 8 + wv * 2 + 1] = (unsigned)(bl >> 32);
        }
    }

    if (t < HID) {
        float a = ldf(in.p[2], t, bf);  // bp
        #pragma unroll
        for (int k = 0; k < 3; k++)
            a += ldf(in.p[0], b * 3 + k, bf) * ldf(in.p[1], k * HID + t, bf);
        ws[OFF_H + b * HID + t] = fmaxf(a, 0.0f);
    }
}

// ---- device-scope grid barrier (generation-counted) ----
__device__ __forceinline__ void gridbar(float* ws) {
    __syncthreads();
    if (threadIdx.x == 0) {
        unsigned* cnt = (unsigned*)(ws + OFF_CNT);
        unsigned* gen = (unsigned*)(ws + OFF_GEN);
        __threadfence();
        unsigned g = __hip_atomic_load(gen, __ATOMIC_ACQUIRE, __HIP_MEMORY_SCOPE_AGENT);
        unsigned a = __hip_atomic_fetch_add(cnt, 1u, __ATOMIC_ACQ_REL, __HIP_MEMORY_SCOPE_AGENT);
        if (a == NBLK - 1) {
            __hip_atomic_store(cnt, 0u, __ATOMIC_RELAXED, __HIP_MEMORY_SCOPE_AGENT);
            __hip_atomic_fetch_add(gen, 1u, __ATOMIC_RELEASE, __HIP_MEMORY_SCOPE_AGENT);
        } else {
            while (__hip_atomic_load(gen, __ATOMIC_ACQUIRE, __HIP_MEMORY_SCOPE_AGENT) == g)
                __builtin_amdgcn_s_sleep(8);
        }
        __threadfence();
    }
    __syncthreads();
}

// ---- fused main ----
// grid 512 x 256 thr (4 waves). Block owns nodes i0, i0+1; wave = head.
// 256-thr + launch_bounds(256,1) => compiler grants ~208 VGPR (r4 precedent,
// WRITE_SIZE confirmed no spills). 512-thr shapes spill at forced 128 (r5/r6).
__global__ __launch_bounds__(256, 1) void k_main(const unsigned* nf, float* ws, void* out) {
    bool bf = detect_bf(nf);
    int t = threadIdx.x;
    int lane = t & 63;
    int h = __builtin_amdgcn_readfirstlane(t >> 6);
    int i0 = blockIdx.x * TIB;

    __shared__ float hs[TIB * HID];
    __shared__ float agg_s[TIB * HID];
    __shared__ unsigned mrow[TIB * 32];

    for (int l = 0; l < NL; l++) {
        // ---- mm3: rows i0, i0+1 of wlh (row-major) + wrt/wvt (transposed) ----
        hs[t] = ws[OFF_H + i0 * HID + t];
        __syncthreads();
        for (int task = t; task < 3 * HID; task += 256) {
            int m = task >> 7, c = task & 127;
            const float* W = ws + ((m == 0) ? OFF_WL : (m == 1) ? OFF_WR : OFF_WVW) + l * HID * HID;
            float a0 = 0, a1 = 0;
            #pragma unroll 4
            for (int k = 0; k < HID; k++) {
                float w = W[k * HID + c];
                a0 = fmaf(hs[k], w, a0);
                a1 = fmaf(hs[HID + k], w, a1);
            }
            if (m == 0) {
                ws[OFF_WLH + (i0 + 0) * HID + c] = a0;
                ws[OFF_WLH + (i0 + 1) * HID + c] = a1;
            } else {
                int doff = (m == 1) ? OFF_WRT : OFF_WVT;
                *(float2*)(ws + doff + c * STRJ + i0) = make_float2(a0, a1);
            }
        }
        gridbar(ws);

        // ---- attention: wave = head h, rows i0 & i0+1, lane = j in 64-chunk ----
        if (t < TIB * 32) mrow[t] = ((const unsigned*)(ws + OFF_MASK))[(i0 + (t >> 5)) * 32 + (t & 31)];
        __syncthreads();

        float att_r[32], wl0[32], wl1[32];
        float cl0 = 0.0f, cl1 = 0.0f;
        {
            const float* attp = ws + OFF_ATT + l * HDD;
            const float* wpa  = ws + OFF_WLH + (i0 + 0) * HID + h * HDD;
            const float* wpb  = ws + OFF_WLH + (i0 + 1) * HID + h * HDD;
            #pragma unroll
            for (int d = 0; d < 32; d++) {
                att_r[d] = attp[d];
                wl0[d] = wpa[d]; cl0 = fmaf(att_r[d], wl0[d], cl0);
                wl1[d] = wpb[d]; cl1 = fmaf(att_r[d], wl1[d], cl1);
            }
        }

        const float* rT = ws + OFF_WRT + h * HDD * STRJ;
        const float* vT = ws + OFF_WVT + h * HDD * STRJ;
        float acc0[32], acc1[32];
        #pragma unroll
        for (int d = 0; d < 32; d++) { acc0[d] = 0.0f; acc1[d] = 0.0f; }
        float ls0 = 0.0f, ls1 = 0.0f;

        #pragma unroll 1
        for (int jc = 0; jc < 16; jc++) {
            int jb = jc * 64 + lane;
            const float* rp = rT + jb;
            const float* vp = vT + jb;
            float vbuf[32];
            float cr = 0.0f, t0 = 0.0f, t1 = 0.0f;
            #pragma unroll
            for (int d = 0; d < 32; d++) {
                float r = rp[d * STRJ];
                vbuf[d] = vp[d * STRJ];
                cr = fmaf(att_r[d], r, cr);
                t0 = fmaf(att_r[d], fabsf(wl0[d] + r), t0);
                t1 = fmaf(att_r[d], fabsf(wl1[d] + r), t1);
            }
            unsigned w0 = mrow[0 * 32 + jc * 2 + (lane >> 5)];
            unsigned w1 = mrow[1 * 32 + jc * 2 + (lane >> 5)];
            float a0 = (float)((w0 >> (lane & 31)) & 1u);
            float a1 = (float)((w1 >> (lane & 31)) & 1u);
            float e0 = fminf(0.6f * (cl0 + cr) + 0.4f * t0, 80.0f);
            float e1 = fminf(0.6f * (cl1 + cr) + 0.4f * t1, 80.0f);
            float pe0 = a0 * __expf(e0);   // exp w/o max-sub: |e| bounded (absmax=0 r4-r6)
            float pe1 = a1 * __expf(e1);
            ls0 += pe0; ls1 += pe1;
            #pragma unroll
            for (int d = 0; d < 32; d++) {
                acc0[d] = fmaf(pe0, vbuf[d], acc0[d]);
                acc1[d] = fmaf(pe1, vbuf[d], acc1[d]);
            }
        }

        #pragma unroll
        for (int off = 32; off > 0; off >>= 1) {
            ls0 += __shfl_xor(ls0, off, 64);
            ls1 += __shfl_xor(ls1, off, 64);
            #pragma unroll
            for (int d = 0; d < 32; d++) {
                acc0[d] += __shfl_xor(acc0[d], off, 64);
                acc1[d] += __shfl_xor(acc1[d], off, 64);
            }
        }
        if (lane == 0) {
            float i0v = 1.0f / ls0, i1v = 1.0f / ls1;
            #pragma unroll
            for (int d = 0; d < 32; d++) {
                agg_s[0 * HID + h * HDD + d] = acc0[d] * i0v;
                agg_s[1 * HID + h * HDD + d] = acc1[d] * i1v;
            }
        }
        __syncthreads();

        // ---- LN + relu + residual: waves 0-1, wave iw -> node i0+iw ----
        if (t < TIB * 64) {
            int iw = t >> 6;
            int i = i0 + iw;
            float v1 = agg_s[iw * HID + lane];
            float v2 = agg_s[iw * HID + 64 + lane];
            float s = v1 + v2, s2 = v1 * v1 + v2 * v2;
            #pragma unroll
            for (int off = 32; off > 0; off >>= 1) {
                s  += __shfl_xor(s,  off, 64);
                s2 += __shfl_xor(s2, off, 64);
            }
            float mu  = s  * (1.0f / HID);
            float var = s2 * (1.0f / HID) - mu * mu;
            float rs = rsqrtf(var + 1e-5f);
            float o1 = (v1 - mu) * rs * ws[OFF_GAM + l * HID + lane]      + ws[OFF_BET + l * HID + lane];
            float o2 = (v2 - mu) * rs * ws[OFF_GAM + l * HID + 64 + lane] + ws[OFF_BET + l * HID + 64 + lane];
            ws[OFF_H + i * HID + lane]      += fmaxf(o1, 0.0f);
            ws[OFF_H + i * HID + 64 + lane] += fmaxf(o2, 0.0f);
        }
        gridbar(ws);
    }

    // ---- heads: waves 0-1, wave iw -> node i0+iw, lane = hidden unit ----
    if (t < TIB * 64) {
        int iw = t >> 6;
        int i = i0 + iw;
        float z1 = ws[OFF_BN1 + lane], zd = ws[OFF_BD1 + lane];
        const float* Wn1 = ws + OFF_WN1;
        const float* Wd1 = ws + OFF_WD1;
        #pragma unroll 4
        for (int k = 0; k < HID; k++) {
            float hk = ws[OFF_H + i * HID + k];
            z1 = fmaf(hk, Wn1[k * 64 + lane], z1);
            zd = fmaf(hk, Wd1[k * 64 + lane], zd);
        }
        z1 = fmaxf(z1, 0.0f); zd = fmaxf(zd, 0.0f);
        float lg = z1 * ws[OFF_WN2 + lane];
        float d0 = zd * ws[OFF_WD2 + lane * 2 + 0];
        float d1 = zd * ws[OFF_WD2 + lane * 2 + 1];
        #pragma unroll
        for (int off = 32; off > 0; off >>= 1) {
            lg += __shfl_xor(lg, off, 64);
            d0 += __shfl_xor(d0, off, 64);
            d1 += __shfl_xor(d1, off, 64);
        }
        if (lane == 0) {
            store_out(out, i,              lg + ws[OFF_BN2],     bf);
            store_out(out, NN + i * 2 + 0, d0 + ws[OFF_BD2 + 0], bf);
            store_out(out, NN + i * 2 + 1, d1 + ws[OFF_BD2 + 1], bf);
        }
    }

    // ---- pooled mean partials + value head ----
    if (t < HID) {
        float s = 0.0f;
        #pragma unroll
        for (int r = 0; r < TIB; r++) s += ws[OFF_H + (i0 + r) * HID + t];
        atomicAdd(&ws[OFF_POOL + t], s);
    }
    gridbar(ws);
    if (blockIdx.x == 0 && t < 64) {
        float z = ws[OFF_BV1 + t];
        #pragma unroll 4
        for (int k = 0; k < HID; k++)
            z = fmaf(ws[OFF_POOL + k] * (1.0f / NN), ws[OFF_WV1 + k * 64 + t], z);
        z = fmaxf(z, 0.0f);
        float pv = z * ws[OFF_WV2 + t];
        #pragma unroll
        for (int off = 32; off > 0; off >>= 1) pv += __shfl_xor(pv, off, 64);
        if (t == 0) store_out(out, 3072, pv + ws[OFF_BV2], bf);
    }
}

extern "C" void kernel_launch(void* const* d_in, const int* in_sizes, int n_in,
                              void* d_out, int out_size, void* d_ws, size_t ws_size,
                              hipStream_t stream) {
    float* ws = (float*)d_ws;
    const unsigned* nf = (const unsigned*)d_in[0];

    P21 ptrs;
    const int map[21] = {0,2,3,4,5,6,7,8,9,10,11,12,13,14,15,16,17,18,19,20,21};
    for (int s = 0; s < 21; s++) ptrs.p[s] = d_in[map[s]];

    k_setup<<<NN, 256, 0, stream>>>(ptrs, d_in[1], nf, ws);
    k_main<<<NBLK, 256, 0, stream>>>(nf, ws, d_out);
}

// Round 8
// 762.118 us; speedup vs baseline: 1.4138x; 1.4138x over previous
//
#include <hip/hip_runtime.h>
#include <hip/hip_bf16.h>

#define NN 1024
#define HID 128
#define NHEADS 4
#define HDD 32
#define NL 3
#define NBLK 256     // 1 block/CU guaranteed => gridbar co-residency
#define TIB 4        // i-rows per block

// ---- ws layout (float-word units), r4 row-major layout ----
constexpr int OFF_CONV = 16;
constexpr int OFF_NF   = OFF_CONV;
constexpr int OFF_WP   = OFF_NF  + 3072;
constexpr int OFF_BP   = OFF_WP  + 384;
constexpr int OFF_WL   = OFF_BP  + 128;
constexpr int OFF_WR   = OFF_WL  + 49152;
constexpr int OFF_WVW  = OFF_WR  + 49152;
constexpr int OFF_ATT  = OFF_WVW + 49152;
constexpr int OFF_GAM  = OFF_ATT + 96;
constexpr int OFF_BET  = OFF_GAM + 384;
constexpr int OFF_WN1  = OFF_BET + 384;
constexpr int OFF_BN1  = OFF_WN1 + 8192;
constexpr int OFF_WN2  = OFF_BN1 + 64;
constexpr int OFF_BN2  = OFF_WN2 + 64;
constexpr int OFF_WD1  = OFF_BN2 + 1;
constexpr int OFF_BD1  = OFF_WD1 + 8192;
constexpr int OFF_WD2  = OFF_BD1 + 64;
constexpr int OFF_BD2  = OFF_WD2 + 128;
constexpr int OFF_WV1  = OFF_BD2 + 2;
constexpr int OFF_BV1  = OFF_WV1 + 8192;
constexpr int OFF_WV2  = OFF_BV1 + 64;
constexpr int OFF_BV2  = OFF_WV2 + 64;
constexpr int OFF_CONV_END = OFF_BV2 + 1;
constexpr int CONV_TOTAL = OFF_CONV_END - OFF_CONV;
constexpr int OFF_MASK = 176960;              // 1024*32 uint32
constexpr int OFF_H    = OFF_MASK + NN*32;
constexpr int OFF_WLH  = OFF_H   + NN*HID;    // row-major [i][hd]
constexpr int OFF_WRH  = OFF_WLH + NN*HID;    // row-major [j][hd]
constexpr int OFF_WVH  = OFF_WRH + NN*HID;    // row-major [j][hd]
constexpr int OFF_POOL = OFF_WVH + NN*HID;
constexpr int OFF_CNT  = OFF_POOL + HID;
constexpr int OFF_GEN  = OFF_CNT + 1;

__device__ __forceinline__ float bf2f(unsigned short u) {
    return __uint_as_float(((unsigned)u) << 16);
}
__device__ __forceinline__ float ldf(const void* p, int idx, bool bf) {
    return bf ? bf2f(((const unsigned short*)p)[idx]) : ((const float*)p)[idx];
}
__device__ __forceinline__ void store_out(void* out, int idx, float v, bool bf) {
    if (bf) {
        unsigned u = __float_as_uint(v);
        unsigned r = (u + 0x7FFFu + ((u >> 16) & 1u)) >> 16;
        ((unsigned short*)out)[idx] = (unsigned short)r;
    } else {
        ((float*)out)[idx] = v;
    }
}
__device__ __forceinline__ bool detect_bf(const unsigned* nf) {
    unsigned w = nf[threadIdx.x & 63];
    int e = (int)((w >> 23) & 0xFFu);
    unsigned long long b = __ballot(e >= 110 && e <= 140);
    return __popcll(b) < 32;
}

struct P21 { const void* p[21]; };
__device__ const int g_sizes[21] = {3072,384,128,49152,49152,49152,96,384,384,
                                    8192,64,64,1,8192,64,128,2,8192,64,64,1};
__device__ const int g_dsts[21] = {OFF_NF,OFF_WP,OFF_BP,OFF_WL,OFF_WR,OFF_WVW,OFF_ATT,
                                   OFF_GAM,OFF_BET,OFF_WN1,OFF_BN1,OFF_WN2,OFF_BN2,
                                   OFF_WD1,OFF_BD1,OFF_WD2,OFF_BD2,OFF_WV1,OFF_BV1,
                                   OFF_WV2,OFF_BV2};

// ---- setup: zero barrier/pool + convert params + adj->bitmask + h0 ----
__global__ __launch_bounds__(256) void k_setup(P21 in, const void* adj, const unsigned* nf,
                                               float* ws) {
    bool bf = detect_bf(nf);
    int b = blockIdx.x, t = threadIdx.x;
    int gid = b * 256 + t;

    if (b == 0 && t < HID + 2) ws[OFF_POOL + t] = 0.0f;

    if (gid < CONV_TOTAL) {
        int rem = gid, s = 0;
        while (s < 21 && rem >= g_sizes[s]) { rem -= g_sizes[s]; s++; }
        if (s < 21) ws[g_dsts[s] + rem] = ldf(in.p[s], rem, bf);
    }

    unsigned* mask = (unsigned*)(ws + OFF_MASK);
    int lane = t & 63, wv = t >> 6;
    for (int p = 0; p < 4; p++) {
        int j = p * 256 + t;
        float v = ldf(adj, b * NN + j, bf);
        unsigned long long bl = __ballot(v > 0.5f);
        if (lane == 0) {
            mask[b * 32 + p * 8 + wv * 2]     = (unsigned)bl;
            mask[b * 32 + p * 8 + wv * 2 + 1] = (unsigned)(bl >> 32);
        }
    }

    if (t < HID) {
        float a = ldf(in.p[2], t, bf);
        #pragma unroll
        for (int k = 0; k < 3; k++)
            a += ldf(in.p[0], b * 3 + k, bf) * ldf(in.p[1], k * HID + t, bf);
        ws[OFF_H + b * HID + t] = fmaxf(a, 0.0f);
    }
}

// ---- device-scope grid barrier ----
__device__ __forceinline__ void gridbar(float* ws) {
    __syncthreads();
    if (threadIdx.x == 0) {
        unsigned* cnt = (unsigned*)(ws + OFF_CNT);
        unsigned* gen = (unsigned*)(ws + OFF_GEN);
        __threadfence();
        unsigned g = __hip_atomic_load(gen, __ATOMIC_ACQUIRE, __HIP_MEMORY_SCOPE_AGENT);
        unsigned a = __hip_atomic_fetch_add(cnt, 1u, __ATOMIC_ACQ_REL, __HIP_MEMORY_SCOPE_AGENT);
        if (a == NBLK - 1) {
            __hip_atomic_store(cnt, 0u, __ATOMIC_RELAXED, __HIP_MEMORY_SCOPE_AGENT);
            __hip_atomic_fetch_add(gen, 1u, __ATOMIC_RELEASE, __HIP_MEMORY_SCOPE_AGENT);
        } else {
            while (__hip_atomic_load(gen, __ATOMIC_ACQUIRE, __HIP_MEMORY_SCOPE_AGENT) == g)
                __builtin_amdgcn_s_sleep(8);
        }
        __threadfence();
    }
    __syncthreads();
}

// ---- fused main: LDS-tiled attention (no big per-lane accumulators) ----
// grid 256 x 256 thr (4 waves). Block owns nodes i0..i0+3.
// Per 64-j tile: stage wrT (LDS, transposed, pad 66) -> phase A (wave=head,
// lane=j: e,P->LDS; wl via LDS broadcasts) -> phase B (thread=(i,col-pair):
// agg += P(LDS multicast) * wv(global coalesced, L1-reused)). Live VGPR ~80.
__global__ __launch_bounds__(256, 1) void k_main(const unsigned* nf, float* ws, void* out) {
    bool bf = detect_bf(nf);
    int t = threadIdx.x;
    int lane = t & 63;
    int h = __builtin_amdgcn_readfirstlane(t >> 6);   // wave id: head (A) / node (LN, heads)
    int i0 = blockIdx.x * TIB;

    __shared__ float wrT[128 * 66];    // transposed wr tile [c][j]
    __shared__ float Pls[16 * 66];     // P[i][h][j]
    __shared__ float wl_s[TIB * HID];
    __shared__ float hs[TIB * HID];
    __shared__ float agg_s[TIB * HID];
    __shared__ float lsum_s[16];
    __shared__ unsigned mrow[TIB * 32];

    if (t < TIB * 32) mrow[t] = ((const unsigned*)(ws + OFF_MASK))[(i0 + (t >> 5)) * 32 + (t & 31)];

    int bi = t >> 6;              // phase-B: i index
    int c2 = (t & 63) * 2;        // phase-B: cols c2, c2+1 (same head)
    int hb = c2 >> 5;             // head of those cols

    for (int l = 0; l < NL; l++) {
        // ---- mm3 (all outputs row-major) ----
        for (int q = t; q < TIB * HID; q += 256) hs[q] = ws[OFF_H + i0 * HID + q];
        __syncthreads();
        for (int task = t; task < 3 * HID; task += 256) {
            int m = task >> 7, c = task & 127;
            const float* W = ws + ((m == 0) ? OFF_WL : (m == 1) ? OFF_WR : OFF_WVW) + l * HID * HID;
            float a0 = 0, a1 = 0, a2 = 0, a3 = 0;
            #pragma unroll 4
            for (int k = 0; k < HID; k++) {
                float w = W[k * HID + c];
                a0 = fmaf(hs[0 * HID + k], w, a0);
                a1 = fmaf(hs[1 * HID + k], w, a1);
                a2 = fmaf(hs[2 * HID + k], w, a2);
                a3 = fmaf(hs[3 * HID + k], w, a3);
            }
            int doff = (m == 0) ? OFF_WLH : (m == 1) ? OFF_WRH : OFF_WVH;
            ws[doff + (i0 + 0) * HID + c] = a0;
            ws[doff + (i0 + 1) * HID + c] = a1;
            ws[doff + (i0 + 2) * HID + c] = a2;
            ws[doff + (i0 + 3) * HID + c] = a3;
        }
        gridbar(ws);

        // ---- per-layer preamble: wl_s, att regs, cl ----
        for (int q = t; q < TIB * HID; q += 256) wl_s[q] = ws[OFF_WLH + i0 * HID + q];
        __syncthreads();
        float4 att4[8];
        {
            const float* attp = ws + OFF_ATT + l * HDD;
            #pragma unroll
            for (int dq = 0; dq < 8; dq++) att4[dq] = *(const float4*)(attp + dq * 4);
        }
        float cl[TIB];
        #pragma unroll
        for (int i = 0; i < TIB; i++) {
            float c_ = 0.0f;
            #pragma unroll
            for (int dq = 0; dq < 8; dq++) {
                float4 w4 = *(const float4*)&wl_s[i * HID + h * HDD + dq * 4];
                float4 a4 = att4[dq];
                c_ += a4.x * w4.x + a4.y * w4.y + a4.z * w4.z + a4.w * w4.w;
            }
            cl[i] = c_;
        }

        float accA = 0.0f, accB = 0.0f;   // phase-B accumulators
        float plsum[TIB] = {0, 0, 0, 0};  // phase-A softmax partials

        #pragma unroll 1
        for (int jt = 0; jt < 16; jt++) {
            // ---- stage: transpose wr tile into LDS ----
            {
                const float* src = ws + OFF_WRH + (jt * 64) * HID;
                #pragma unroll
                for (int k = 0; k < 8; k++) {
                    int q = k * 256 + t;
                    int j = q >> 5, c4 = (q & 31) * 4;
                    float4 w = *(const float4*)(src + j * HID + c4);
                    wrT[(c4 + 0) * 66 + j] = w.x;
                    wrT[(c4 + 1) * 66 + j] = w.y;
                    wrT[(c4 + 2) * 66 + j] = w.z;
                    wrT[(c4 + 3) * 66 + j] = w.w;
                }
            }
            __syncthreads();
            // ---- phase A: e + P (wave = head, lane = j) ----
            {
                float cr = 0.f, tt0 = 0.f, tt1 = 0.f, tt2 = 0.f, tt3 = 0.f;
                #pragma unroll
                for (int dq = 0; dq < 8; dq++) {
                    int cbase = h * HDD + dq * 4;
                    float r0 = wrT[(cbase + 0) * 66 + lane];
                    float r1 = wrT[(cbase + 1) * 66 + lane];
                    float r2 = wrT[(cbase + 2) * 66 + lane];
                    float r3 = wrT[(cbase + 3) * 66 + lane];
                    float4 a4 = att4[dq];
                    cr += a4.x * r0 + a4.y * r1 + a4.z * r2 + a4.w * r3;
                    float4 w0 = *(const float4*)&wl_s[0 * HID + cbase];
                    float4 w1 = *(const float4*)&wl_s[1 * HID + cbase];
                    float4 w2 = *(const float4*)&wl_s[2 * HID + cbase];
                    float4 w3 = *(const float4*)&wl_s[3 * HID + cbase];
                    tt0 += a4.x*fabsf(w0.x+r0) + a4.y*fabsf(w0.y+r1) + a4.z*fabsf(w0.z+r2) + a4.w*fabsf(w0.w+r3);
                    tt1 += a4.x*fabsf(w1.x+r0) + a4.y*fabsf(w1.y+r1) + a4.z*fabsf(w1.z+r2) + a4.w*fabsf(w1.w+r3);
                    tt2 += a4.x*fabsf(w2.x+r0) + a4.y*fabsf(w2.y+r1) + a4.z*fabsf(w2.z+r2) + a4.w*fabsf(w2.w+r3);
                    tt3 += a4.x*fabsf(w3.x+r0) + a4.y*fabsf(w3.y+r1) + a4.z*fabsf(w3.z+r2) + a4.w*fabsf(w3.w+r3);
                }
                int mw = jt * 2 + (lane >> 5);
                int sh = lane & 31;
                float e, pe;
                e = fminf(0.6f * (cl[0] + cr) + 0.4f * tt0, 80.f);
                pe = (float)((mrow[0 * 32 + mw] >> sh) & 1u) * __expf(e);
                plsum[0] += pe; Pls[(0 * 4 + h) * 66 + lane] = pe;
                e = fminf(0.6f * (cl[1] + cr) + 0.4f * tt1, 80.f);
                pe = (float)((mrow[1 * 32 + mw] >> sh) & 1u) * __expf(e);
                plsum[1] += pe; Pls[(1 * 4 + h) * 66 + lane] = pe;
                e = fminf(0.6f * (cl[2] + cr) + 0.4f * tt2, 80.f);
                pe = (float)((mrow[2 * 32 + mw] >> sh) & 1u) * __expf(e);
                plsum[2] += pe; Pls[(2 * 4 + h) * 66 + lane] = pe;
                e = fminf(0.6f * (cl[3] + cr) + 0.4f * tt3, 80.f);
                pe = (float)((mrow[3 * 32 + mw] >> sh) & 1u) * __expf(e);
                plsum[3] += pe; Pls[(3 * 4 + h) * 66 + lane] = pe;
            }
            __syncthreads();
            // ---- phase B: agg += P * wv (wv direct global, coalesced) ----
            {
                const float* wvb = ws + OFF_WVH + (jt * 64) * HID + c2;
                const float* prow = &Pls[(bi * 4 + hb) * 66];
                #pragma unroll 4
                for (int j = 0; j < 64; j++) {
                    float p = prow[j];
                    float2 v = *(const float2*)(wvb + j * HID);
                    accA = fmaf(p, v.x, accA);
                    accB = fmaf(p, v.y, accB);
                }
            }
        }

        // ---- lsum reduce + normalize into agg_s ----
        #pragma unroll
        for (int off = 32; off > 0; off >>= 1) {
            #pragma unroll
            for (int i = 0; i < TIB; i++) plsum[i] += __shfl_xor(plsum[i], off, 64);
        }
        if (lane == 0) {
            #pragma unroll
            for (int i = 0; i < TIB; i++) lsum_s[i * 4 + h] = plsum[i];
        }
        __syncthreads();
        {
            float inv = 1.0f / lsum_s[bi * 4 + hb];
            agg_s[bi * HID + c2]     = accA * inv;
            agg_s[bi * HID + c2 + 1] = accB * inv;
        }
        __syncthreads();

        // ---- LN + relu + residual: wave iw -> node i0+iw ----
        {
            int iw = t >> 6;
            int i = i0 + iw;
            float v1 = agg_s[iw * HID + lane];
            float v2 = agg_s[iw * HID + 64 + lane];
            float s = v1 + v2, s2 = v1 * v1 + v2 * v2;
            #pragma unroll
            for (int off = 32; off > 0; off >>= 1) {
                s  += __shfl_xor(s,  off, 64);
                s2 += __shfl_xor(s2, off, 64);
            }
            float mu  = s  * (1.0f / HID);
            float var = s2 * (1.0f / HID) - mu * mu;
            float rs = rsqrtf(var + 1e-5f);
            float o1 = (v1 - mu) * rs * ws[OFF_GAM + l * HID + lane]      + ws[OFF_BET + l * HID + lane];
            float o2 = (v2 - mu) * rs * ws[OFF_GAM + l * HID + 64 + lane] + ws[OFF_BET + l * HID + 64 + lane];
            ws[OFF_H + i * HID + lane]      += fmaxf(o1, 0.0f);
            ws[OFF_H + i * HID + 64 + lane] += fmaxf(o2, 0.0f);
        }
        gridbar(ws);
    }

    // ---- heads: wave iw -> node i0+iw, lane = hidden unit ----
    {
        int iw = t >> 6;
        int i = i0 + iw;
        float z1 = ws[OFF_BN1 + lane], zd = ws[OFF_BD1 + lane];
        const float* Wn1 = ws + OFF_WN1;
        const float* Wd1 = ws + OFF_WD1;
        #pragma unroll 4
        for (int k = 0; k < HID; k++) {
            float hk = ws[OFF_H + i * HID + k];
            z1 = fmaf(hk, Wn1[k * 64 + lane], z1);
            zd = fmaf(hk, Wd1[k * 64 + lane], zd);
        }
        z1 = fmaxf(z1, 0.0f); zd = fmaxf(zd, 0.0f);
        float lg = z1 * ws[OFF_WN2 + lane];
        float d0 = zd * ws[OFF_WD2 + lane * 2 + 0];
        float d1 = zd * ws[OFF_WD2 + lane * 2 + 1];
        #pragma unroll
        for (int off = 32; off > 0; off >>= 1) {
            lg += __shfl_xor(lg, off, 64);
            d0 += __shfl_xor(d0, off, 64);
            d1 += __shfl_xor(d1, off, 64);
        }
        if (lane == 0) {
            store_out(out, i,              lg + ws[OFF_BN2],     bf);
            store_out(out, NN + i * 2 + 0, d0 + ws[OFF_BD2 + 0], bf);
            store_out(out, NN + i * 2 + 1, d1 + ws[OFF_BD2 + 1], bf);
        }
    }

    // ---- pooled mean partials + value head ----
    if (t < HID) {
        float s = 0.0f;
        #pragma unroll
        for (int r = 0; r < TIB; r++) s += ws[OFF_H + (i0 + r) * HID + t];
        atomicAdd(&ws[OFF_POOL + t], s);
    }
    gridbar(ws);
    if (blockIdx.x == 0 && t < 64) {
        float z = ws[OFF_BV1 + t];
        #pragma unroll 4
        for (int k = 0; k < HID; k++)
            z = fmaf(ws[OFF_POOL + k] * (1.0f / NN), ws[OFF_WV1 + k * 64 + t], z);
        z = fmaxf(z, 0.0f);
        float pv = z * ws[OFF_WV2 + t];
        #pragma unroll
        for (int off = 32; off > 0; off >>= 1) pv += __shfl_xor(pv, off, 64);
        if (t == 0) store_out(out, 3072, pv + ws[OFF_BV2], bf);
    }
}

extern "C" void kernel_launch(void* const* d_in, const int* in_sizes, int n_in,
                              void* d_out, int out_size, void* d_ws, size_t ws_size,
                              hipStream_t stream) {
    float* ws = (float*)d_ws;
    const unsigned* nf = (const unsigned*)d_in[0];

    P21 ptrs;
    const int map[21] = {0,2,3,4,5,6,7,8,9,10,11,12,13,14,15,16,17,18,19,20,21};
    for (int s = 0; s < 21; s++) ptrs.p[s] = d_in[map[s]];

    k_setup<<<NN, 256, 0, stream>>>(ptrs, d_in[1], nf, ws);
    k_main<<<NBLK, 256, 0, stream>>>(nf, ws, d_out);
}